// Round 3
// baseline (348.651 us; speedup 1.0000x reference)
//
#include <hip/hip_runtime.h>
#include <math.h>

#define BB 8
#define TT 4096
#define DDIM 512
#define KK 4096
#define NN (BB*TT)
#define EPS 0.05f
#define CMAX 16384

typedef __attribute__((ext_vector_type(8))) short bf16x8;
typedef __attribute__((ext_vector_type(4))) float f32x4;

__device__ __forceinline__ void async16(void* lds, const void* g) {
  __builtin_amdgcn_global_load_lds((const __attribute__((address_space(1))) void*)g,
                                   (__attribute__((address_space(3))) void*)lds, 16, 0, 0);
}

__device__ __forceinline__ unsigned pk_bf16(float a, float b) {
  unsigned ua = __float_as_uint(a); ua += 0x7FFFu + ((ua >> 16) & 1u);
  unsigned ub = __float_as_uint(b); ub += 0x7FFFu + ((ub >> 16) & 1u);
  return (ua >> 16) | (ub & 0xFFFF0000u);
}

// ---------- fused prep: bf16 convert + row stats for BOTH inputs, zero cnt ----------
__global__ __launch_bounds__(256) void prep_kernel(const float* __restrict__ x,
                                                   const float* __restrict__ embed,
                                                   short* __restrict__ xb,
                                                   short* __restrict__ eb,
                                                   float* __restrict__ inv2,
                                                   float* __restrict__ esq,
                                                   int* __restrict__ cnt) {
  if (blockIdx.x == 0 && threadIdx.x == 0) *cnt = 0;
  const float* src; short* dst; float* outv; int r; int mode;
  if (blockIdx.x < KK / 4) {
    src = embed; dst = eb; outv = esq; mode = 0;
    r = blockIdx.x * 4 + (threadIdx.x >> 6);
  } else {
    src = x; dst = xb; outv = inv2; mode = 1;
    r = (blockIdx.x - KK / 4) * 4 + (threadIdx.x >> 6);
  }
  int lane = threadIdx.x & 63;
  const float4* row4 = (const float4*)(src + (size_t)r * DDIM);
  float4 v0 = row4[lane];
  float4 v1 = row4[lane + 64];
  uint2 p0, p1;
  p0.x = pk_bf16(v0.x, v0.y); p0.y = pk_bf16(v0.z, v0.w);
  p1.x = pk_bf16(v1.x, v1.y); p1.y = pk_bf16(v1.z, v1.w);
  *(uint2*)(dst + (size_t)r * DDIM + lane * 4) = p0;
  *(uint2*)(dst + (size_t)r * DDIM + 256 + lane * 4) = p1;
  float ss = v0.x*v0.x + v0.y*v0.y + v0.z*v0.z + v0.w*v0.w
           + v1.x*v1.x + v1.y*v1.y + v1.z*v1.z + v1.w*v1.w;
  #pragma unroll
  for (int off = 32; off; off >>= 1) ss += __shfl_down(ss, off);
  if (lane == 0) outv[r] = mode ? 2.0f / fmaxf(sqrtf(ss), 1e-12f) : ss;
}

// ---------- main MFMA pass: 128x256 tile, approx scores + per-row top-2 ----------
// grid 1024: bid&255 = m-block (128 rows), bid>>8 = k-quarter (1024 codes)
__global__ __launch_bounds__(256, 2) void vq_mfma(const short* __restrict__ xb,
                                                  const short* __restrict__ eb,
                                                  const float* __restrict__ esq,
                                                  const float* __restrict__ inv2,
                                                  float4* __restrict__ top2) {
  __shared__ short As[128 * 64];
  __shared__ short Bs[256 * 64];
  __shared__ float rS1[2][128];
  __shared__ float rS2[2][128];
  __shared__ int   rI1[2][128];

  const int tid = threadIdx.x;
  const int lane = tid & 63;
  const int w = tid >> 6;
  const int wr = w >> 1, wc = w & 1;     // wave tile: 64 rows x 128 cols
  const int q = lane >> 4, c16 = lane & 15;

  const int mb = blockIdx.x & 255;
  const int kq = blockIdx.x >> 8;
  const int n0 = mb * 128;
  const int kbase = kq * 1024;

  // staging: lane fills LDS row (base + lane>>3), 16B chunk (lane&7);
  // global column chunk XOR-swizzled by (lane>>3)&7 -> LDS[row][c] holds chunk c^(row&7)
  const int srow = lane >> 3;
  const int scol = ((lane & 7) ^ srow) * 8;
  const short* gA = xb + (size_t)(n0 + w * 32 + srow) * DDIM + scol;

  float s1[16], s2v[16];
  int   i1[16];
  #pragma unroll
  for (int s = 0; s < 16; ++s) { s1[s] = -3e38f; s2v[s] = -3e38f; i1[s] = 0; }

  f32x4 inv4[4];
  #pragma unroll
  for (int ti = 0; ti < 4; ++ti)
    inv4[ti] = *(const f32x4*)&inv2[n0 + wr * 64 + ti * 16 + q * 4];

  for (int c = 0; c < 4; ++c) {
    const int k0c = kbase + c * 256;
    const short* gB = eb + (size_t)(k0c + w * 64 + srow) * DDIM + scol;
    f32x4 acc[4][8];
    #pragma unroll
    for (int ti = 0; ti < 4; ++ti)
      #pragma unroll
      for (int tj = 0; tj < 8; ++tj) acc[ti][tj] = (f32x4){0.f, 0.f, 0.f, 0.f};

    for (int d0 = 0; d0 < DDIM; d0 += 64) {
      #pragma unroll
      for (int i = 0; i < 4; ++i)
        async16(As + (w * 32 + i * 8) * 64, gA + (size_t)i * 8 * DDIM + d0);
      #pragma unroll
      for (int i = 0; i < 8; ++i)
        async16(Bs + (w * 64 + i * 8) * 64, gB + (size_t)i * 8 * DDIM + d0);
      __syncthreads();
      #pragma unroll
      for (int ks = 0; ks < 2; ++ks) {
        const int ko = (((ks << 2) | q) ^ (lane & 7)) << 3;  // swizzled k-chunk
        bf16x8 af[4];
        #pragma unroll
        for (int ti = 0; ti < 4; ++ti)
          af[ti] = *(const bf16x8*)&As[(wr * 64 + ti * 16 + c16) * 64 + ko];
        #pragma unroll
        for (int h = 0; h < 2; ++h) {     // two halves of 4 B-frags: caps live regs
          bf16x8 bf[4];
          #pragma unroll
          for (int j = 0; j < 4; ++j)
            bf[j] = *(const bf16x8*)&Bs[(wc * 128 + (h * 4 + j) * 16 + c16) * 64 + ko];
          #pragma unroll
          for (int ti = 0; ti < 4; ++ti)
            #pragma unroll
            for (int j = 0; j < 4; ++j)
              acc[ti][h * 4 + j] = __builtin_amdgcn_mfma_f32_16x16x32_bf16(
                  af[ti], bf[j], acc[ti][h * 4 + j], 0, 0, 0);
        }
      }
      __syncthreads();
    }
    // epilogue: score = acc*inv2 - esq, update per-row top-2
    #pragma unroll
    for (int tj = 0; tj < 8; ++tj) {
      const int col = k0c + wc * 128 + tj * 16 + c16;
      const float nes = -esq[col];
      #pragma unroll
      for (int ti = 0; ti < 4; ++ti)
        #pragma unroll
        for (int r = 0; r < 4; ++r) {
          int slot = ti * 4 + r;
          float sc = fmaf(acc[ti][tj][r], inv4[ti][r], nes);
          float mn = fminf(sc, s1[slot]);
          s2v[slot] = fmaxf(s2v[slot], mn);
          if (sc > s1[slot]) { s1[slot] = sc; i1[slot] = col; }
        }
    }
  }

  // reduce across the 16 lanes sharing each row
  #pragma unroll
  for (int slot = 0; slot < 16; ++slot) {
    float a1 = s1[slot], a2 = s2v[slot]; int ai = i1[slot];
    #pragma unroll
    for (int off = 1; off < 16; off <<= 1) {
      float b1 = __shfl_xor(a1, off);
      float b2 = __shfl_xor(a2, off);
      int   bi = __shfl_xor(ai, off);
      float mn = fminf(a1, b1);
      a2 = fmaxf(fmaxf(a2, b2), mn);
      if (b1 > a1 || (b1 == a1 && bi < ai)) { a1 = b1; ai = bi; }
    }
    if (c16 == 0) {
      int row = wr * 64 + (slot >> 2) * 16 + q * 4 + (slot & 3);
      rS1[wc][row] = a1; rS2[wc][row] = a2; rI1[wc][row] = ai;
    }
  }
  __syncthreads();
  if (tid < 128) {
    float a1 = rS1[0][tid], a2 = rS2[0][tid]; int ai = rI1[0][tid];
    float b1 = rS1[1][tid], b2 = rS2[1][tid]; int bi = rI1[1][tid];
    float mn = fminf(a1, b1);
    a2 = fmaxf(fmaxf(a2, b2), mn);
    if (b1 > a1 || (b1 == a1 && bi < ai)) { a1 = b1; ai = bi; }
    top2[(size_t)kq * NN + n0 + tid] = make_float4(a1, __int_as_float(ai), a2, 0.f);
  }
}

// ---------- finalize: merge 4 k-quarters, write idx, flag small-margin rows ----------
__global__ __launch_bounds__(256) void finalize_kernel(const float4* __restrict__ top2,
                                                       float* __restrict__ out_ind,
                                                       int* __restrict__ flags,
                                                       int* __restrict__ list,
                                                       int* __restrict__ cnt) {
  int row = blockIdx.x * 256 + threadIdx.x;
  float a1 = -3e38f, a2 = -3e38f; int ai = 0;
  #pragma unroll
  for (int kq = 0; kq < 4; ++kq) {
    float4 t = top2[(size_t)kq * NN + row];
    float b1 = t.x, b2 = t.z; int bi = __float_as_int(t.y);
    float mn = fminf(a1, b1);
    a2 = fmaxf(fmaxf(a2, b2), mn);
    if (b1 > a1 || (b1 == a1 && bi < ai)) { a1 = b1; ai = bi; }
  }
  out_ind[row] = (float)ai;
  int f = 0;
  if (a1 - a2 < EPS) {
    int p = atomicAdd(cnt, 1);
    if (p < CMAX) { list[p] = row; f = p + 1; }
  }
  flags[row] = f;
}

// ---------- cleanup: exact fp32 rescore, row-tiled (16 rows staged in LDS) ----------
// grid 512: bid>>5 = code chunk (256 codes), bid&31 = row-tile slot
__global__ __launch_bounds__(256) void cleanup_kernel(const float* __restrict__ x,
                                                      const float* __restrict__ embed,
                                                      const float* __restrict__ esq,
                                                      const float* __restrict__ inv2,
                                                      const int* __restrict__ list,
                                                      const int* __restrict__ cnt,
                                                      float2* __restrict__ exact) {
  __shared__ float xr[16][DDIM];
  __shared__ float xiv[16];
  __shared__ int   rid[16];
  __shared__ float red_s[4][16];
  __shared__ int   red_i[4][16];
  const int kc = blockIdx.x >> 5;
  const int slot = blockIdx.x & 31;
  const int tid = threadIdx.x;
  const int lane = tid & 63, w = tid >> 6;
  int n = *cnt; if (n > CMAX) n = CMAX;
  const int code = kc * 256 + tid;
  const float4* erow = (const float4*)&embed[(size_t)code * DDIM];
  const float nes = -esq[code];

  for (int tile = slot; tile * 16 < n; tile += 32) {
    __syncthreads();
    if (tid < 16) {
      int pos = tile * 16 + tid;
      int row = (pos < n) ? list[pos] : list[0];
      rid[tid] = row;
      xiv[tid] = inv2[row];
    }
    __syncthreads();
    #pragma unroll
    for (int i = 0; i < 8; ++i) {
      int idx = tid + i * 256;
      int rl = idx >> 7, d4 = idx & 127;
      ((float4*)xr[rl])[d4] = *(const float4*)&x[(size_t)rid[rl] * DDIM + d4 * 4];
    }
    __syncthreads();
    float acc[16];
    #pragma unroll
    for (int r = 0; r < 16; ++r) acc[r] = 0.f;
    for (int d4 = 0; d4 < 128; ++d4) {
      float4 e4 = erow[d4];
      #pragma unroll
      for (int r = 0; r < 16; ++r) {
        float4 x4 = ((const float4*)xr[r])[d4];
        acc[r] += e4.x * x4.x + e4.y * x4.y + e4.z * x4.z + e4.w * x4.w;
      }
    }
    #pragma unroll
    for (int r = 0; r < 16; ++r) {
      float bs = fmaf(acc[r], xiv[r], nes);
      int bi = code;
      #pragma unroll
      for (int off = 1; off < 64; off <<= 1) {
        float b1 = __shfl_xor(bs, off);
        int   b2 = __shfl_xor(bi, off);
        if (b1 > bs || (b1 == bs && b2 < bi)) { bs = b1; bi = b2; }
      }
      if (lane == 0) { red_s[w][r] = bs; red_i[w][r] = bi; }
    }
    __syncthreads();
    if (tid < 16) {
      float bs = red_s[0][tid]; int bi = red_i[0][tid];
      #pragma unroll
      for (int ww = 1; ww < 4; ++ww) {
        float b1 = red_s[ww][tid]; int b2 = red_i[ww][tid];
        if (b1 > bs || (b1 == bs && b2 < bi)) { bs = b1; bi = b2; }
      }
      int pos = tile * 16 + tid;
      if (pos < n) exact[(size_t)pos * 16 + kc] = make_float2(bs, (float)bi);
    }
  }
}

// ---------- gather + transpose (merges exact results for flagged rows) ----------
__global__ __launch_bounds__(256) void gather_kernel(const float* __restrict__ embed,
                                                     const int* __restrict__ flags,
                                                     const float2* __restrict__ exact,
                                                     float* __restrict__ out_ind,
                                                     float* __restrict__ out_q) {
  __shared__ int lidx[64];
  __shared__ float trans[64 * 65];
  const int n0 = blockIdx.x * 64;
  const int tid = threadIdx.x;
  if (tid < 64) {
    const int row = n0 + tid;
    const int f = flags[row];
    int idx;
    if (f) {
      float bsv = -3e38f; int bi = 0;
      const float2* e16 = &exact[(size_t)(f - 1) * 16];
      #pragma unroll
      for (int k = 0; k < 16; ++k) {
        float2 t = e16[k];
        int ci = (int)t.y;
        if (t.x > bsv || (t.x == bsv && ci < bi)) { bsv = t.x; bi = ci; }
      }
      idx = bi;
      out_ind[row] = (float)idx;
    } else {
      idx = (int)out_ind[row];
    }
    lidx[tid] = idx;
  }
  __syncthreads();
  const int bb = n0 >> 12;
  const int t0 = n0 & (TT - 1);
  const int w = tid >> 6, lane = tid & 63;
  for (int d0 = 0; d0 < DDIM; d0 += 64) {
    if (d0) __syncthreads();
    #pragma unroll
    for (int qq = 0; qq < 16; ++qq) {
      int tt2 = w * 16 + qq;
      int e = lidx[tt2];
      trans[lane * 65 + tt2] = embed[(size_t)e * DDIM + d0 + lane];
    }
    __syncthreads();
    #pragma unroll
    for (int qq = 0; qq < 4; ++qq) {
      int dl = (tid >> 4) * 4 + qq;
      int t4 = (tid & 15) * 4;
      float4 o;
      o.x = trans[dl * 65 + t4 + 0];
      o.y = trans[dl * 65 + t4 + 1];
      o.z = trans[dl * 65 + t4 + 2];
      o.w = trans[dl * 65 + t4 + 3];
      *(float4*)&out_q[((size_t)bb * DDIM + d0 + dl) * TT + t0 + t4] = o;
    }
  }
}

extern "C" void kernel_launch(void* const* d_in, const int* in_sizes, int n_in,
                              void* d_out, int out_size, void* d_ws, size_t ws_size,
                              hipStream_t stream) {
  const float* x     = (const float*)d_in[0];
  const float* embed = (const float*)d_in[1];
  char* ws = (char*)d_ws;
  short* xb      = (short*)(ws);                 // 33,554,432 B
  short* eb      = (short*)(ws + 33554432);      //  4,194,304 B
  float* esq     = (float*)(ws + 37748736);      //     16,384 B
  float* inv2    = (float*)(ws + 37765120);      //    131,072 B
  float4* top2   = (float4*)(ws + 37896192);     //  2,097,152 B
  int* list      = (int*)(ws + 39993344);        //     65,536 B
  int* flags     = (int*)(ws + 40058880);        //    131,072 B
  float2* exact  = (float2*)(ws + 40189952);     //  2,097,152 B
  int* cnt       = (int*)(ws + 42287104);        //          4 B

  float* out_ind = (float*)d_out;
  float* out_q   = out_ind + NN;

  prep_kernel<<<KK / 4 + NN / 4, 256, 0, stream>>>(x, embed, xb, eb, inv2, esq, cnt);
  vq_mfma<<<1024, 256, 0, stream>>>(xb, eb, esq, inv2, top2);
  finalize_kernel<<<NN / 256, 256, 0, stream>>>(top2, out_ind, flags, list, cnt);
  cleanup_kernel<<<512, 256, 0, stream>>>(x, embed, esq, inv2, list, cnt, exact);
  gather_kernel<<<NN / 64, 256, 0, stream>>>(embed, flags, exact, out_ind, out_q);
}